// Round 7
// baseline (457.073 us; speedup 1.0000x reference)
//
#include <hip/hip_runtime.h>

typedef unsigned short ushort_t;
typedef __attribute__((ext_vector_type(8))) short short8;
typedef __attribute__((ext_vector_type(4))) float f32x4;
typedef __attribute__((ext_vector_type(8))) unsigned short us8;
typedef __attribute__((ext_vector_type(4))) unsigned short us4;

#define SEQ 2048
#define HIDD 2048
#define XLD 3072
#define SCALING 0.08838834764831843f

__device__ __forceinline__ float bf2f(ushort_t u) {
    unsigned int x = ((unsigned int)u) << 16;
    return __builtin_bit_cast(float, x);
}
__device__ __forceinline__ ushort_t f2bf(float f) {
    unsigned int u = __builtin_bit_cast(unsigned int, f);
    u += 0x7fffu + ((u >> 16) & 1u);
    return (ushort_t)(u >> 16);
}

// ------- Transpose + convert: W (K x N) f32 row-major -> Wt rows, bf16 -------
__device__ __forceinline__ void transpose_tile(
    const float* __restrict__ W, ushort_t* __restrict__ Wt,
    int N, int n0, int k0, int dstRow0) {
    __shared__ ushort_t t[64 * 80];
    const int tid = threadIdx.x;
    {
        const int kl = tid >> 4;          // 0..15
        const int nc = (tid & 15) * 4;    // 0..60
        #pragma unroll
        for (int p = 0; p < 4; ++p) {
            int k = kl + p * 16;
            float4 v = *(const float4*)(W + (size_t)(k0 + k) * N + n0 + nc);
            t[(nc + 0) * 80 + k] = f2bf(v.x);
            t[(nc + 1) * 80 + k] = f2bf(v.y);
            t[(nc + 2) * 80 + k] = f2bf(v.z);
            t[(nc + 3) * 80 + k] = f2bf(v.w);
        }
    }
    __syncthreads();
    {
        const int nl = tid >> 3;          // 0..31
        const int kc = (tid & 7) * 8;     // 0..56
        #pragma unroll
        for (int p = 0; p < 2; ++p) {
            int n = nl + p * 32;
            *(us8*)(Wt + (size_t)(dstRow0 + n) * HIDD + k0 + kc) =
                *(const us8*)&t[n * 80 + kc];
        }
    }
}

// All four weight transposes + the hidden f32->bf16 convert in ONE launch.
__global__ __launch_bounds__(256) void transpose_all(
    const float* __restrict__ Wq, const float* __restrict__ Wk,
    const float* __restrict__ Wv, const float* __restrict__ Wo,
    const float* __restrict__ hid,
    ushort_t* __restrict__ Wqkvt, ushort_t* __restrict__ Wot,
    ushort_t* __restrict__ Hb) {
    int bx = blockIdx.x, k0 = blockIdx.y * 64;
    if (bx < 32)       transpose_tile(Wq, Wqkvt, 2048, bx * 64,        k0, bx * 64);
    else if (bx < 40)  transpose_tile(Wk, Wqkvt, 512,  (bx - 32) * 64, k0, 2048 + (bx - 32) * 64);
    else if (bx < 48)  transpose_tile(Wv, Wqkvt, 512,  (bx - 40) * 64, k0, 2560 + (bx - 40) * 64);
    else if (bx < 80)  transpose_tile(Wo, Wot,   2048, (bx - 48) * 64, k0, (bx - 48) * 64);
    else {
        int chunk = (bx - 80) * 32 + blockIdx.y;   // 0..1023, 4096 floats each
        size_t base = (size_t)chunk * 4096 + threadIdx.x * 16;
        #pragma unroll
        for (int p = 0; p < 4; ++p) {
            float4 v = *(const float4*)(hid + base + p * 4);
            us4 o;
            o[0] = f2bf(v.x); o[1] = f2bf(v.y); o[2] = f2bf(v.z); o[3] = f2bf(v.w);
            *(us4*)(Hb + base + p * 4) = o;
        }
    }
}

// -------- GEMM split-K: P[z] (MxN bf16) = A(:, koff..) * Bt(:, koff..)^T -----
// Proven 128x128 / BK=64 / 4-wave / 3-blocks-per-CU structure.
// NT stores on P: the partial stream is read-once (reducers NT-load it);
// keeping it out of L2 leaves the re-read operand panels (Hb/Wqkvt/Am/Wot,
// 16-24x reuse, ~21 MB -> L2-resident) cached across the GEMM.
__global__ __launch_bounds__(256, 3) void gemm_splitk(
    const ushort_t* __restrict__ A, int lda,
    const ushort_t* __restrict__ Bt, int ldb,
    ushort_t* __restrict__ P, int ldc,
    const int4 kexts) {
    __shared__ ushort_t lA[2 * 128 * 32];
    __shared__ ushort_t lB[2 * 128 * 32];
    const int tid = threadIdx.x;
    const int wave = tid >> 6, lane = tid & 63;
    const int wm = wave >> 1, wn = wave & 1;
    const int quad = lane >> 4, l16 = lane & 15;
    const int m0 = blockIdx.y * 128, n0 = blockIdx.x * 128;
    const int z = blockIdx.z;

    const int ke[4] = {kexts.x, kexts.y, kexts.z, kexts.w};
    int koff = 0;
    for (int zz = 0; zz < 4; ++zz) if (zz < z) koff += ke[zz];
    const int kext = ke[z];

    A  += (size_t)koff;
    Bt += (size_t)koff;
    P  += (size_t)z * ((size_t)gridDim.y * 128) * ldc;

    const int srow = lane >> 2;                      // 0..15
    const int scol = 8 * ((lane & 3) ^ (srow & 3));  // swizzled 16B col-block

    f32x4 acc[4][4] = {};

    const ushort_t* Ab = A  + (size_t)(m0 + wave * 16 + srow) * lda + scol;
    const ushort_t* Bb = Bt + (size_t)(n0 + wave * 16 + srow) * ldb + scol;
    ushort_t* lAw = lA + (wave * 16) * 32;
    ushort_t* lBw = lB + (wave * 16) * 32;

    const int rsw = (quad ^ (l16 & 3)) * 8;

    for (int kk = 0; kk < kext; kk += 64) {
        __syncthreads();
        #pragma unroll
        for (int kh = 0; kh < 2; ++kh) {
            #pragma unroll
            for (int c = 0; c < 2; ++c) {
                __builtin_amdgcn_global_load_lds(
                    (const __attribute__((address_space(1))) unsigned int*)(const void*)
                        (Ab + (size_t)(c * 64) * lda + kk + kh * 32),
                    (__attribute__((address_space(3))) unsigned int*)(void*)
                        (lAw + kh * 128 * 32 + c * 64 * 32), 16, 0, 0);
                __builtin_amdgcn_global_load_lds(
                    (const __attribute__((address_space(1))) unsigned int*)(const void*)
                        (Bb + (size_t)(c * 64) * ldb + kk + kh * 32),
                    (__attribute__((address_space(3))) unsigned int*)(void*)
                        (lBw + kh * 128 * 32 + c * 64 * 32), 16, 0, 0);
            }
        }
        __syncthreads();
        #pragma unroll
        for (int kh = 0; kh < 2; ++kh) {
            short8 af[4], bfr[4];
            #pragma unroll
            for (int mt = 0; mt < 4; ++mt)
                af[mt] = *(const short8*)&lA[kh * 128 * 32 + (wm * 64 + mt * 16 + l16) * 32 + rsw];
            #pragma unroll
            for (int nt = 0; nt < 4; ++nt)
                bfr[nt] = *(const short8*)&lB[kh * 128 * 32 + (wn * 64 + nt * 16 + l16) * 32 + rsw];
            #pragma unroll
            for (int mt = 0; mt < 4; ++mt) {
                #pragma unroll
                for (int nt = 0; nt < 4; ++nt)
                    acc[mt][nt] = __builtin_amdgcn_mfma_f32_16x16x32_bf16(
                        af[mt], bfr[nt], acc[mt][nt], 0, 0, 0);
            }
        }
    }

    #pragma unroll
    for (int mt = 0; mt < 4; ++mt) {
        #pragma unroll
        for (int nt = 0; nt < 4; ++nt) {
            int gm = m0 + wm * 64 + mt * 16 + quad * 4;
            int gn = n0 + wn * 64 + nt * 16 + l16;
            #pragma unroll
            for (int r = 0; r < 4; ++r)
                __builtin_nontemporal_store(
                    f2bf(acc[mt][nt][r]), &P[(size_t)(gm + r) * ldc + gn]);
        }
    }
}

// ---- Fused split-K(2) reduce for X: RoPE path (Q/K cols) + V path -----------
// NT loads on P (read-once stream): don't evict X/Wot from L2.
#define RWAVES (SEQ * 10)   /* RoPE region: cols 0..2559, 10 x 256-col spans */
#define VWAVES (SEQ * 2)    /* V region:    cols 2560..3071, 2 x 256-col spans */
__global__ __launch_bounds__(256) void reduce_x(
    const ushort_t* __restrict__ P, ushort_t* __restrict__ X,
    const float* __restrict__ cosp, const float* __restrict__ sinp) {
    const size_t ZS = (size_t)SEQ * XLD;
    int wbase = (blockIdx.x * 4 + (threadIdx.x >> 6)) * 4;
    int lane = threadIdx.x & 63;
    #pragma unroll
    for (int pp = 0; pp < 4; ++pp) {
        int wid = wbase + pp;
        if (wid < RWAVES) {
            int s = wid / 10, seg = wid % 10;
            int c0 = seg * 256 + lane * 4;          // 4 contiguous cols per lane
            size_t base = (size_t)s * XLD + c0;
            us4 a = __builtin_nontemporal_load((const us4*)(P + base));
            us4 b = __builtin_nontemporal_load((const us4*)(P + ZS + base));
            float x[4];
            #pragma unroll
            for (int t = 0; t < 4; ++t) x[t] = bf2f(a[t]) + bf2f(b[t]);
            float p[4];
            #pragma unroll
            for (int t = 0; t < 4; ++t) p[t] = __shfl_xor(x[t], 16, 64);
            int d = (lane * 4) & 127;               // within-head col
            float4 cv = *(const float4*)(cosp + (size_t)s * 128 + d);
            float4 sv = *(const float4*)(sinp + (size_t)s * 128 + d);
            float sgn = (lane & 16) ? 1.f : -1.f;   // hi half: +x1*sin, lo: -x2*sin
            us4 o;
            o[0] = f2bf(x[0] * cv.x + sgn * p[0] * sv.x);
            o[1] = f2bf(x[1] * cv.y + sgn * p[1] * sv.y);
            o[2] = f2bf(x[2] * cv.z + sgn * p[2] * sv.z);
            o[3] = f2bf(x[3] * cv.w + sgn * p[3] * sv.w);
            *(us4*)(X + base) = o;
        } else {
            int w2 = wid - RWAVES;                  // 0..VWAVES-1
            int s = w2 >> 1;
            int c0 = 2560 + (w2 & 1) * 256 + lane * 4;
            size_t base = (size_t)s * XLD + c0;
            us4 a = __builtin_nontemporal_load((const us4*)(P + base));
            us4 b = __builtin_nontemporal_load((const us4*)(P + ZS + base));
            us4 o;
            #pragma unroll
            for (int t = 0; t < 4; ++t) o[t] = f2bf(bf2f(a[t]) + bf2f(b[t]));
            *(us4*)(X + base) = o;
        }
    }
}

// ---- Split-K(3) reduce for the final output (bf16 partials -> f32 out) ------
// NT loads (read-once partials) + NT stores (out never re-read on device).
__global__ __launch_bounds__(256) void reduce_out3(
    const ushort_t* __restrict__ P, float* __restrict__ out) {
    const size_t ZS = (size_t)SEQ * HIDD;
    size_t idx0 = ((size_t)blockIdx.x * 256 + threadIdx.x) * 16;
    #pragma unroll
    for (int pp = 0; pp < 4; ++pp) {
        size_t idx = idx0 + pp * 4;
        us4 a = __builtin_nontemporal_load((const us4*)(P + idx));
        us4 b = __builtin_nontemporal_load((const us4*)(P + ZS + idx));
        us4 c = __builtin_nontemporal_load((const us4*)(P + 2 * ZS + idx));
        f32x4 o;
        o[0] = bf2f(a[0]) + bf2f(b[0]) + bf2f(c[0]);
        o[1] = bf2f(a[1]) + bf2f(b[1]) + bf2f(c[1]);
        o[2] = bf2f(a[2]) + bf2f(b[2]) + bf2f(c[2]);
        o[3] = bf2f(a[3]) + bf2f(b[3]) + bf2f(c[3]);
        __builtin_nontemporal_store(o, (f32x4*)(out + idx));
    }
}

// ---------------- Attention: one block per (head h, 16 queries) --------------
// K/V staged in LDS (104 rows x 272 B, XOR segment swizzle). Weight-row write
// skips the cross-lane shfl machinery for segments that are provably all-zero
// (band spans <=2 of 8 segments; sinks live in segment 0; predicate is
// wave-uniform). NT stores on the 268 MB write-once weights stream.
#define SMLD 136
__device__ __forceinline__ float qk_round_lds(
    const char* __restrict__ smb, const float* qf,
    int jg, int dg, int lo, int nsink, int w0, int r) {
    int jj = r * 16 + jg;
    int row;
    if (jj < nsink) row = 48 + jj;
    else {
        int widx = lo + jj - nsink - w0;
        if (widx > 47) widx = 47;           // OOB slots clamped (masked later)
        row = widx;
    }
    const char* base = smb + row * 272 + ((dg * 64) ^ ((row & 3) << 6));
    float p = 0.f;
    #pragma unroll
    for (int pq = 0; pq < 4; ++pq) {
        us8 v = *(const us8*)(base + pq * 16);
        #pragma unroll
        for (int t = 0; t < 8; ++t) p += qf[pq * 8 + t] * bf2f(v[t]);
    }
    p += __shfl_xor(p, 1, 64);
    p += __shfl_xor(p, 2, 64);
    return p * SCALING;
}

__global__ __launch_bounds__(256) void attn_kernel(
    const ushort_t* __restrict__ X, float* __restrict__ Wts,
    ushort_t* __restrict__ Aout) {
    __shared__ ushort_t sm[104 * SMLD];
    char* smb = (char*)sm;
    const int tid = threadIdx.x;
    const int lane = tid & 63;
    const int wv = tid >> 6;
    const int h = blockIdx.x >> 7;
    const int i0 = (blockIdx.x & 127) << 4;
    const int w0 = (i0 >= 32) ? (i0 - 32) : 0;
    const int kvh = h >> 2;

    const ushort_t* Kg = X + 2048 + kvh * 128;
    const ushort_t* Vg = X + 2560 + kvh * 128;

    // stage: 104 row-tasks, 16 threads x 16 B each, swizzled dst segments
    #pragma unroll
    for (int p = 0; p < 7; ++p) {
        int tau = p * 16 + (tid >> 4);
        if (tau < 104) {
            int rr = (tau < 52) ? tau : (tau - 52);
            int grow = (rr < 48) ? (w0 + rr) : (rr - 48);
            const ushort_t* src = ((tau < 52) ? Kg : Vg) + (size_t)grow * XLD + (tid & 15) * 8;
            int dst = tau * 272 + (((tid & 15) * 16) ^ ((tau & 3) << 6));
            *(us8*)(smb + dst) = *(const us8*)src;
        }
    }
    __syncthreads();

    const int dg = lane & 3;      // 32-dim segment owner within 4-lane group
    const int jg = lane >> 2;     // j-slot group 0..15

    for (int ii = 0; ii < 4; ++ii) {
        const int i = i0 + wv * 4 + ii;

        // this lane's 32-dim quarter of Q, unpacked to f32
        float qf[32];
        {
            const ushort_t* Q = X + (size_t)i * XLD + h * 128 + dg * 32;
            #pragma unroll
            for (int pq = 0; pq < 4; ++pq) {
                us8 v = *(const us8*)(Q + pq * 8);
                #pragma unroll
                for (int t = 0; t < 8; ++t) qf[pq * 8 + t] = bf2f(v[t]);
            }
        }

        int lo = i - 32; if (lo < 0) lo = 0;
        int nsink = lo < 4 ? lo : 4;
        int NJ = nsink + (i - lo + 1);          // <= 37

        float s0 = qk_round_lds(smb, qf, jg, dg, lo, nsink, w0, 0);
        float s1 = qk_round_lds(smb, qf, jg, dg, lo, nsink, w0, 1);
        float s2 = qk_round_lds(smb, qf, jg, dg, lo, nsink, w0, 2);

        // gather: lane l takes score of slot l (round l>>4, group l&15, dg=0)
        int src = (lane & 15) * 4;
        float m0 = __shfl(s0, src, 64);
        float m1 = __shfl(s1, src, 64);
        float m2 = __shfl(s2, src, 64);
        float mysc = (lane < 16) ? m0 : ((lane < 32) ? m1 : m2);
        if (lane >= NJ) mysc = -1e30f;

        float m = mysc;
        #pragma unroll
        for (int off = 32; off > 0; off >>= 1) m = fmaxf(m, __shfl_xor(m, off, 64));

        float e = (lane < NJ) ? expf(mysc - m) : 0.f;
        float l = e;
        #pragma unroll
        for (int off = 32; off > 0; off >>= 1) l += __shfl_xor(l, off, 64);
        float w = e / l;   // lane jj holds weight for slot jj (jj < NJ)

        // dense weights row: 2048 f32 = 8 segments x (64 lanes x float4), NT.
        // Only segment 0 (sinks) and the 1-2 segments containing [lo, i] can
        // hold nonzeros; all others are pure zero stores (no shfl).
        const int sA = lo >> 8, sB = i >> 8;
        float* row = Wts + ((size_t)h * SEQ + i) * SEQ;
        #pragma unroll
        for (int s = 0; s < 8; ++s) {
            f32x4 o;
            bool active = (s == 0 && nsink > 0) || (s >= sA && s <= sB);
            if (active) {
                #pragma unroll
                for (int t = 0; t < 4; ++t) {
                    int c = s * 256 + lane * 4 + t;
                    bool in = (c < nsink) || (c >= lo && c <= i);
                    int jjc = in ? ((c < nsink) ? c : (nsink + c - lo)) : 0;
                    float wv2 = __shfl(w, jjc, 64);
                    o[t] = in ? wv2 : 0.f;
                }
            } else {
                o[0] = 0.f; o[1] = 0.f; o[2] = 0.f; o[3] = 0.f;
            }
            __builtin_nontemporal_store(o, (f32x4*)(row + s * 256 + lane * 4));
        }

        // PV from LDS (V rows 52..103), swizzle-aware dword reads
        float o0 = 0.f, o1 = 0.f;
        for (int jj = 0; jj < NJ; ++jj) {
            int vrow;
            if (jj < nsink) vrow = 100 + jj;
            else {
                int widx = lo + jj - nsink - w0;
                vrow = 52 + widx;
            }
            float pb = __shfl(w, jj, 64);
            unsigned int vv = *(const unsigned int*)
                (smb + vrow * 272 + ((4 * lane) ^ ((vrow & 3) << 6)));
            o0 += pb * bf2f((ushort_t)(vv & 0xffff));
            o1 += pb * bf2f((ushort_t)(vv >> 16));
        }
        int r = h * 128 + (i >> 4);
        int c = (i & 15) * 128 + 2 * lane;
        ushort_t* Ar = Aout + (size_t)r * HIDD + c;
        Ar[0] = f2bf(o0);
        Ar[1] = f2bf(o1);
    }
}

extern "C" void kernel_launch(void* const* d_in, const int* in_sizes, int n_in,
                              void* d_out, int out_size, void* d_ws, size_t ws_size,
                              hipStream_t stream) {
    if (n_in < 7) return;
    const float* hid  = (const float*)d_in[0];
    const float* cosp = (const float*)d_in[1];
    const float* sinp = (const float*)d_in[2];
    const float* Wq   = (const float*)d_in[3];
    const float* Wk   = (const float*)d_in[4];
    const float* Wv   = (const float*)d_in[5];
    const float* Wo   = (const float*)d_in[6];

    float* out = (float*)d_out;                  // attn_output (f32)
    float* wts = out + (size_t)SEQ * HIDD;       // attn_weights (f32)

    // workspace layout (all bf16 elems)
    ushort_t* Hb    = (ushort_t*)d_ws;                    // 2048x2048
    ushort_t* Wqkvt = Hb    + (size_t)2048 * 2048;        // 3072x2048
    ushort_t* Wot   = Wqkvt + (size_t)3072 * 2048;        // 2048x2048
    ushort_t* X     = Wot   + (size_t)2048 * 2048;        // 2048x3072
    ushort_t* Am    = X     + (size_t)SEQ * XLD;          // 2048x2048
    ushort_t* Pqkv  = Am    + (size_t)SEQ * HIDD;         // 2 x 2048x3072
    ushort_t* Pout  = Pqkv  + 2 * (size_t)SEQ * XLD;      // 3 x 2048x2048
    size_t need = ((char*)(Pout + 3 * (size_t)SEQ * HIDD)) - (char*)d_ws;
    if (ws_size < need) return;

    dim3 blk(256);
    // all weight transposes + hidden convert in one launch
    transpose_all<<<dim3(112, 32), blk, 0, stream>>>(
        Wq, Wk, Wv, Wo, hid, Wqkvt, Wot, Hb);

    // fused QKV projection, split-K=2 (1024+1024) -> bf16 partials
    gemm_splitk<<<dim3(24, 16, 2), blk, 0, stream>>>(
        Hb, HIDD, Wqkvt, 2048, Pqkv, XLD, make_int4(1024, 1024, 0, 0));
    reduce_x<<<(RWAVES + VWAVES) / 16, blk, 0, stream>>>(
        Pqkv, X, cosp, sinp);

    // attention: one block per (h, 16 queries), K/V staged in LDS
    attn_kernel<<<SEQ * 16 / 16, blk, 0, stream>>>(X, wts, Am);

    // output projection, split-K=3 (704+704+640, all x64, full residency)
    gemm_splitk<<<dim3(16, 16, 3), blk, 0, stream>>>(
        Am, HIDD, Wot, 2048, Pout, HIDD, make_int4(704, 704, 640, 0));
    reduce_out3<<<(SEQ * HIDD) / (256 * 16), blk, 0, stream>>>(Pout, out);
}

// Round 8
// 450.115 us; speedup vs baseline: 1.0155x; 1.0155x over previous
//
#include <hip/hip_runtime.h>

typedef unsigned short ushort_t;
typedef __attribute__((ext_vector_type(8))) short short8;
typedef __attribute__((ext_vector_type(4))) float f32x4;
typedef __attribute__((ext_vector_type(8))) unsigned short us8;
typedef __attribute__((ext_vector_type(4))) unsigned short us4;

#define SEQ 2048
#define HIDD 2048
#define XLD 3072
#define SCALING 0.08838834764831843f

__device__ __forceinline__ float bf2f(ushort_t u) {
    unsigned int x = ((unsigned int)u) << 16;
    return __builtin_bit_cast(float, x);
}
__device__ __forceinline__ ushort_t f2bf(float f) {
    unsigned int u = __builtin_bit_cast(unsigned int, f);
    u += 0x7fffu + ((u >> 16) & 1u);
    return (ushort_t)(u >> 16);
}

// ------- Transpose + convert: W (K x N) f32 row-major -> Wt rows, bf16 -------
__device__ __forceinline__ void transpose_tile(
    const float* __restrict__ W, ushort_t* __restrict__ Wt,
    int N, int n0, int k0, int dstRow0) {
    __shared__ ushort_t t[64 * 80];
    const int tid = threadIdx.x;
    {
        const int kl = tid >> 4;          // 0..15
        const int nc = (tid & 15) * 4;    // 0..60
        #pragma unroll
        for (int p = 0; p < 4; ++p) {
            int k = kl + p * 16;
            float4 v = *(const float4*)(W + (size_t)(k0 + k) * N + n0 + nc);
            t[(nc + 0) * 80 + k] = f2bf(v.x);
            t[(nc + 1) * 80 + k] = f2bf(v.y);
            t[(nc + 2) * 80 + k] = f2bf(v.z);
            t[(nc + 3) * 80 + k] = f2bf(v.w);
        }
    }
    __syncthreads();
    {
        const int nl = tid >> 3;          // 0..31
        const int kc = (tid & 7) * 8;     // 0..56
        #pragma unroll
        for (int p = 0; p < 2; ++p) {
            int n = nl + p * 32;
            *(us8*)(Wt + (size_t)(dstRow0 + n) * HIDD + k0 + kc) =
                *(const us8*)&t[n * 80 + kc];
        }
    }
}

// All four weight transposes + the hidden f32->bf16 convert in ONE launch.
__global__ __launch_bounds__(256) void transpose_all(
    const float* __restrict__ Wq, const float* __restrict__ Wk,
    const float* __restrict__ Wv, const float* __restrict__ Wo,
    const float* __restrict__ hid,
    ushort_t* __restrict__ Wqkvt, ushort_t* __restrict__ Wot,
    ushort_t* __restrict__ Hb) {
    int bx = blockIdx.x, k0 = blockIdx.y * 64;
    if (bx < 32)       transpose_tile(Wq, Wqkvt, 2048, bx * 64,        k0, bx * 64);
    else if (bx < 40)  transpose_tile(Wk, Wqkvt, 512,  (bx - 32) * 64, k0, 2048 + (bx - 32) * 64);
    else if (bx < 48)  transpose_tile(Wv, Wqkvt, 512,  (bx - 40) * 64, k0, 2560 + (bx - 40) * 64);
    else if (bx < 80)  transpose_tile(Wo, Wot,   2048, (bx - 48) * 64, k0, (bx - 48) * 64);
    else {
        int chunk = (bx - 80) * 32 + blockIdx.y;   // 0..1023, 4096 floats each
        size_t base = (size_t)chunk * 4096 + threadIdx.x * 16;
        #pragma unroll
        for (int p = 0; p < 4; ++p) {
            float4 v = *(const float4*)(hid + base + p * 4);
            us4 o;
            o[0] = f2bf(v.x); o[1] = f2bf(v.y); o[2] = f2bf(v.z); o[3] = f2bf(v.w);
            *(us4*)(Hb + base + p * 4) = o;
        }
    }
}

// -------- GEMM split-K: P[z] (MxN bf16) = A(:, koff..) * Bt(:, koff..)^T -----
__global__ __launch_bounds__(256) void gemm_splitk(
    const ushort_t* __restrict__ A, int lda,
    const ushort_t* __restrict__ Bt, int ldb,
    ushort_t* __restrict__ P, int ldc,
    const int4 kexts) {
    __shared__ ushort_t lA[2 * 128 * 32];
    __shared__ ushort_t lB[2 * 128 * 32];
    const int tid = threadIdx.x;
    const int wave = tid >> 6, lane = tid & 63;
    const int wm = wave >> 1, wn = wave & 1;
    const int quad = lane >> 4, l16 = lane & 15;
    const int m0 = blockIdx.y * 128, n0 = blockIdx.x * 128;
    const int z = blockIdx.z;

    const int ke[4] = {kexts.x, kexts.y, kexts.z, kexts.w};
    int koff = 0;
    for (int zz = 0; zz < 4; ++zz) if (zz < z) koff += ke[zz];
    const int kext = ke[z];

    A  += (size_t)koff;
    Bt += (size_t)koff;
    P  += (size_t)z * ((size_t)gridDim.y * 128) * ldc;

    const int srow = lane >> 2;                      // 0..15
    const int scol = 8 * ((lane & 3) ^ (srow & 3));  // swizzled 16B col-block

    f32x4 acc[4][4] = {};

    const ushort_t* Ab = A  + (size_t)(m0 + wave * 16 + srow) * lda + scol;
    const ushort_t* Bb = Bt + (size_t)(n0 + wave * 16 + srow) * ldb + scol;
    ushort_t* lAw = lA + (wave * 16) * 32;
    ushort_t* lBw = lB + (wave * 16) * 32;

    const int rsw = (quad ^ (l16 & 3)) * 8;

    for (int kk = 0; kk < kext; kk += 64) {
        __syncthreads();
        #pragma unroll
        for (int kh = 0; kh < 2; ++kh) {
            #pragma unroll
            for (int c = 0; c < 2; ++c) {
                __builtin_amdgcn_global_load_lds(
                    (const __attribute__((address_space(1))) unsigned int*)(const void*)
                        (Ab + (size_t)(c * 64) * lda + kk + kh * 32),
                    (__attribute__((address_space(3))) unsigned int*)(void*)
                        (lAw + kh * 128 * 32 + c * 64 * 32), 16, 0, 0);
                __builtin_amdgcn_global_load_lds(
                    (const __attribute__((address_space(1))) unsigned int*)(const void*)
                        (Bb + (size_t)(c * 64) * ldb + kk + kh * 32),
                    (__attribute__((address_space(3))) unsigned int*)(void*)
                        (lBw + kh * 128 * 32 + c * 64 * 32), 16, 0, 0);
            }
        }
        __syncthreads();
        #pragma unroll
        for (int kh = 0; kh < 2; ++kh) {
            short8 af[4], bfr[4];
            #pragma unroll
            for (int mt = 0; mt < 4; ++mt)
                af[mt] = *(const short8*)&lA[kh * 128 * 32 + (wm * 64 + mt * 16 + l16) * 32 + rsw];
            #pragma unroll
            for (int nt = 0; nt < 4; ++nt)
                bfr[nt] = *(const short8*)&lB[kh * 128 * 32 + (wn * 64 + nt * 16 + l16) * 32 + rsw];
            #pragma unroll
            for (int mt = 0; mt < 4; ++mt) {
                #pragma unroll
                for (int nt = 0; nt < 4; ++nt)
                    acc[mt][nt] = __builtin_amdgcn_mfma_f32_16x16x32_bf16(
                        af[mt], bfr[nt], acc[mt][nt], 0, 0, 0);
            }
        }
    }

    #pragma unroll
    for (int mt = 0; mt < 4; ++mt) {
        #pragma unroll
        for (int nt = 0; nt < 4; ++nt) {
            int gm = m0 + wm * 64 + mt * 16 + quad * 4;
            int gn = n0 + wn * 64 + nt * 16 + l16;
            #pragma unroll
            for (int r = 0; r < 4; ++r)
                P[(size_t)(gm + r) * ldc + gn] = f2bf(acc[mt][nt][r]);
        }
    }
}

// ---- Fused split-K(2) reduce for X: RoPE path (Q/K cols) + V path -----------
#define RWAVES (SEQ * 10)   /* RoPE region: cols 0..2559, 10 x 256-col spans */
#define VWAVES (SEQ * 2)    /* V region:    cols 2560..3071, 2 x 256-col spans */
__global__ __launch_bounds__(256) void reduce_x(
    const ushort_t* __restrict__ P, ushort_t* __restrict__ X,
    const float* __restrict__ cosp, const float* __restrict__ sinp) {
    const size_t ZS = (size_t)SEQ * XLD;
    int wid = blockIdx.x * 4 + (threadIdx.x >> 6);
    int lane = threadIdx.x & 63;
    if (wid < RWAVES) {
        int s = wid / 10, seg = wid % 10;
        int c0 = seg * 256 + lane * 4;          // 4 contiguous cols per lane
        size_t base = (size_t)s * XLD + c0;
        us4 a = *(const us4*)(P + base);
        us4 b = *(const us4*)(P + ZS + base);
        float x[4];
        #pragma unroll
        for (int t = 0; t < 4; ++t) x[t] = bf2f(a[t]) + bf2f(b[t]);
        float p[4];
        #pragma unroll
        for (int t = 0; t < 4; ++t) p[t] = __shfl_xor(x[t], 16, 64);
        int d = (lane * 4) & 127;               // within-head col
        float4 cv = *(const float4*)(cosp + (size_t)s * 128 + d);
        float4 sv = *(const float4*)(sinp + (size_t)s * 128 + d);
        float sgn = (lane & 16) ? 1.f : -1.f;   // hi half: +x1*sin, lo: -x2*sin
        us4 o;
        o[0] = f2bf(x[0] * cv.x + sgn * p[0] * sv.x);
        o[1] = f2bf(x[1] * cv.y + sgn * p[1] * sv.y);
        o[2] = f2bf(x[2] * cv.z + sgn * p[2] * sv.z);
        o[3] = f2bf(x[3] * cv.w + sgn * p[3] * sv.w);
        *(us4*)(X + base) = o;
    } else {
        int w2 = wid - RWAVES;                  // 0..VWAVES-1
        int s = w2 >> 1;
        int c0 = 2560 + (w2 & 1) * 256 + lane * 4;
        size_t base = (size_t)s * XLD + c0;
        us4 a = *(const us4*)(P + base);
        us4 b = *(const us4*)(P + ZS + base);
        us4 o;
        #pragma unroll
        for (int t = 0; t < 4; ++t) o[t] = f2bf(bf2f(a[t]) + bf2f(b[t]));
        *(us4*)(X + base) = o;
    }
}

// ---- Split-K(3) reduce for the final output (bf16 partials -> f32 out) ------
__global__ __launch_bounds__(256) void reduce_out3(
    const ushort_t* __restrict__ P, float* __restrict__ out) {
    const size_t ZS = (size_t)SEQ * HIDD;
    size_t idx = ((size_t)blockIdx.x * 256 + threadIdx.x) * 4;
    us4 a = *(const us4*)(P + idx);
    us4 b = *(const us4*)(P + ZS + idx);
    us4 c = *(const us4*)(P + 2 * ZS + idx);
    float4 o;
    o.x = bf2f(a[0]) + bf2f(b[0]) + bf2f(c[0]);
    o.y = bf2f(a[1]) + bf2f(b[1]) + bf2f(c[1]);
    o.z = bf2f(a[2]) + bf2f(b[2]) + bf2f(c[2]);
    o.w = bf2f(a[3]) + bf2f(b[3]) + bf2f(c[3]);
    *(float4*)(out + idx) = o;
}

// ---------------- Attention: one block per (head h, 16 queries) --------------
// The 16 queries i0..i0+15 share a 48-row K/V window [w0, w0+47] plus sink
// rows 0..3. Stage all 104 rows (52 K + 52 V) in LDS once (row stride 136
// ushorts = 272 B = 17 x 16 B -> consecutive rows land on distinct 16 B
// bank-slots, so the 16-row qk read is 2-way = free). Then each of the 4
// waves processes 4 queries entirely from LDS.
#define SMLD 136
__device__ __forceinline__ float qk_round_lds(
    const ushort_t* __restrict__ sm, const float* qf,
    int jg, int dg, int lo, int nsink, int w0, int r) {
    int jj = r * 16 + jg;
    int row;
    if (jj < nsink) row = 48 + jj;
    else {
        int widx = lo + jj - nsink - w0;
        if (widx > 47) widx = 47;           // OOB slots clamped (masked later)
        row = widx;
    }
    const ushort_t* kp = sm + row * SMLD + dg * 32;
    float p = 0.f;
    #pragma unroll
    for (int pq = 0; pq < 4; ++pq) {
        us8 v = *(const us8*)(kp + pq * 8);
        #pragma unroll
        for (int t = 0; t < 8; ++t) p += qf[pq * 8 + t] * bf2f(v[t]);
    }
    p += __shfl_xor(p, 1, 64);
    p += __shfl_xor(p, 2, 64);
    return p * SCALING;
}

__global__ __launch_bounds__(256) void attn_kernel(
    const ushort_t* __restrict__ X, float* __restrict__ Wts,
    ushort_t* __restrict__ Aout) {
    __shared__ ushort_t sm[104 * SMLD];
    const int tid = threadIdx.x;
    const int lane = tid & 63;
    const int wv = tid >> 6;
    const int h = blockIdx.x >> 7;
    const int i0 = (blockIdx.x & 127) << 4;
    const int w0 = (i0 >= 32) ? (i0 - 32) : 0;
    const int kvh = h >> 2;

    const ushort_t* Kg = X + 2048 + kvh * 128;
    const ushort_t* Vg = X + 2560 + kvh * 128;

    // stage: 104 row-tasks, 16 threads x 16 B each
    #pragma unroll
    for (int p = 0; p < 7; ++p) {
        int tau = p * 16 + (tid >> 4);
        if (tau < 104) {
            int rr = (tau < 52) ? tau : (tau - 52);
            int grow = (rr < 48) ? (w0 + rr) : (rr - 48);
            const ushort_t* src = ((tau < 52) ? Kg : Vg) + (size_t)grow * XLD + (tid & 15) * 8;
            *(us8*)&sm[tau * SMLD + (tid & 15) * 8] = *(const us8*)src;
        }
    }
    __syncthreads();

    const int dg = lane & 3;      // 32-dim segment owner within 4-lane group
    const int jg = lane >> 2;     // j-slot group 0..15

    for (int ii = 0; ii < 4; ++ii) {
        const int i = i0 + wv * 4 + ii;

        // this lane's 32-dim quarter of Q, unpacked to f32
        float qf[32];
        {
            const ushort_t* Q = X + (size_t)i * XLD + h * 128 + dg * 32;
            #pragma unroll
            for (int pq = 0; pq < 4; ++pq) {
                us8 v = *(const us8*)(Q + pq * 8);
                #pragma unroll
                for (int t = 0; t < 8; ++t) qf[pq * 8 + t] = bf2f(v[t]);
            }
        }

        int lo = i - 32; if (lo < 0) lo = 0;
        int nsink = lo < 4 ? lo : 4;
        int NJ = nsink + (i - lo + 1);          // <= 37

        float s0 = qk_round_lds(sm, qf, jg, dg, lo, nsink, w0, 0);
        float s1 = qk_round_lds(sm, qf, jg, dg, lo, nsink, w0, 1);
        float s2 = qk_round_lds(sm, qf, jg, dg, lo, nsink, w0, 2);

        // gather: lane l takes score of slot l (round l>>4, group l&15, dg=0)
        int src = (lane & 15) * 4;
        float m0 = __shfl(s0, src, 64);
        float m1 = __shfl(s1, src, 64);
        float m2 = __shfl(s2, src, 64);
        float mysc = (lane < 16) ? m0 : ((lane < 32) ? m1 : m2);
        if (lane >= NJ) mysc = -1e30f;

        float m = mysc;
        #pragma unroll
        for (int off = 32; off > 0; off >>= 1) m = fmaxf(m, __shfl_xor(m, off, 64));

        float e = (lane < NJ) ? expf(mysc - m) : 0.f;
        float l = e;
        #pragma unroll
        for (int off = 32; off > 0; off >>= 1) l += __shfl_xor(l, off, 64);
        float w = e / l;   // lane jj holds weight for slot jj (jj < NJ)

        // dense weights row: 2048 f32 = 8 slots x (64 lanes x float4)
        float* row = Wts + ((size_t)h * SEQ + i) * SEQ;
        #pragma unroll
        for (int s = 0; s < 8; ++s) {
            float4 o;
            #pragma unroll
            for (int t = 0; t < 4; ++t) {
                int c = s * 256 + lane * 4 + t;
                bool in = (c < nsink) || (c >= lo && c <= i);
                int jjc = in ? ((c < nsink) ? c : (nsink + c - lo)) : 0;
                float wv2 = __shfl(w, jjc, 64);
                o[t] = in ? wv2 : 0.f;
            }
            *(float4*)(row + s * 256 + lane * 4) = o;
        }

        // PV from LDS (V rows 52..103)
        float o0 = 0.f, o1 = 0.f;
        for (int jj = 0; jj < NJ; ++jj) {
            int vrow;
            if (jj < nsink) vrow = 100 + jj;
            else {
                int widx = lo + jj - nsink - w0;
                vrow = 52 + widx;
            }
            float pb = __shfl(w, jj, 64);
            unsigned int vv = *(const unsigned int*)&sm[vrow * SMLD + 2 * lane];
            o0 += pb * bf2f((ushort_t)(vv & 0xffff));
            o1 += pb * bf2f((ushort_t)(vv >> 16));
        }
        int r = h * 128 + (i >> 4);
        int c = (i & 15) * 128 + 2 * lane;
        ushort_t* Ar = Aout + (size_t)r * HIDD + c;
        Ar[0] = f2bf(o0);
        Ar[1] = f2bf(o1);
    }
}

extern "C" void kernel_launch(void* const* d_in, const int* in_sizes, int n_in,
                              void* d_out, int out_size, void* d_ws, size_t ws_size,
                              hipStream_t stream) {
    if (n_in < 7) return;
    const float* hid  = (const float*)d_in[0];
    const float* cosp = (const float*)d_in[1];
    const float* sinp = (const float*)d_in[2];
    const float* Wq   = (const float*)d_in[3];
    const float* Wk   = (const float*)d_in[4];
    const float* Wv   = (const float*)d_in[5];
    const float* Wo   = (const float*)d_in[6];

    float* out = (float*)d_out;                  // attn_output (f32)
    float* wts = out + (size_t)SEQ * HIDD;       // attn_weights (f32)

    // workspace layout (all bf16 elems)
    ushort_t* Hb    = (ushort_t*)d_ws;                    // 2048x2048
    ushort_t* Wqkvt = Hb    + (size_t)2048 * 2048;        // 3072x2048
    ushort_t* Wot   = Wqkvt + (size_t)3072 * 2048;        // 2048x2048
    ushort_t* X     = Wot   + (size_t)2048 * 2048;        // 2048x3072
    ushort_t* Am    = X     + (size_t)SEQ * XLD;          // 2048x2048
    ushort_t* Pqkv  = Am    + (size_t)SEQ * HIDD;         // 2 x 2048x3072
    ushort_t* Pout  = Pqkv  + 2 * (size_t)SEQ * XLD;      // 3 x 2048x2048
    size_t need = ((char*)(Pout + 3 * (size_t)SEQ * HIDD)) - (char*)d_ws;
    if (ws_size < need) return;

    dim3 blk(256);
    // all weight transposes + hidden convert in one launch
    transpose_all<<<dim3(112, 32), blk, 0, stream>>>(
        Wq, Wk, Wv, Wo, hid, Wqkvt, Wot, Hb);

    // fused QKV projection, split-K=2 (1024+1024) -> bf16 partials
    gemm_splitk<<<dim3(24, 16, 2), blk, 0, stream>>>(
        Hb, HIDD, Wqkvt, 2048, Pqkv, XLD, make_int4(1024, 1024, 0, 0));
    reduce_x<<<(RWAVES + VWAVES) / 4, blk, 0, stream>>>(
        Pqkv, X, cosp, sinp);

    // attention: one block per (h, 16 queries), K/V staged in LDS
    attn_kernel<<<SEQ * 16 / 16, blk, 0, stream>>>(X, wts, Am);

    // output projection, split-K=3 (704+704+640, all x64, full residency)
    gemm_splitk<<<dim3(16, 16, 3), blk, 0, stream>>>(
        Am, HIDD, Wot, 2048, Pout, HIDD, make_int4(704, 704, 640, 0));
    reduce_out3<<<(SEQ * HIDD) / (256 * 4), blk, 0, stream>>>(Pout, out);
}